// Round 2
// baseline (414.037 us; speedup 1.0000x reference)
//
#include <hip/hip_runtime.h>
#include <math.h>

#define BDIM 256

constexpr int Bc = 2, Vc = 20000, Cc = 32, NBc = 12, KSc = 9, OUTc = 32;
constexpr int NTASK = Bc * Vc;                 // 40000
constexpr int TPG   = 3;                        // tasks per group-iteration
constexpr int NTRIP = (NTASK + TPG - 1) / TPG;  // 13334
constexpr int GPB   = 8;                        // 32-lane groups per block
constexpr int WPAD  = 292;                      // row stride: %4==0 (b128 aligned), %32==4 (conflict-free)
constexpr int UXP   = 12;                       // padded ux row (16B-aligned float4 loads)

// ---------------- kernel 1: ux[row,k] = sum_c x[row,c] * u[c,k] ----------------
__global__ __launch_bounds__(BDIM)
void ux_kernel(const float* __restrict__ x, const float* __restrict__ u,
               float* __restrict__ ux)
{
    __shared__ float us[Cc * KSc];
    for (int i = threadIdx.x; i < Cc * KSc; i += BDIM) us[i] = u[i];
    __syncthreads();

    const int row = blockIdx.x * BDIM + threadIdx.x;
    if (row >= NTASK) return;

    const float4* xr = (const float4*)(x + row * Cc);
    float4 xv[8];
#pragma unroll
    for (int i = 0; i < 8; ++i) xv[i] = xr[i];

    float acc[KSc];
#pragma unroll
    for (int k = 0; k < KSc; ++k) acc[k] = 0.f;
#pragma unroll
    for (int c = 0; c < Cc; ++c) {
        const float xc = ((const float*)xv)[c];
#pragma unroll
        for (int k = 0; k < KSc; ++k) acc[k] = fmaf(xc, us[c * KSc + k], acc[k]);
    }
    float4* o4 = (float4*)(ux + row * UXP);
    o4[0] = make_float4(acc[0], acc[1], acc[2], acc[3]);
    o4[1] = make_float4(acc[4], acc[5], acc[6], acc[7]);
    o4[2] = make_float4(acc[8], 0.f, 0.f, 0.f);
}

// butterfly transpose-reduce: lane c enters with z[0..31]; lane o returns sum_c z_c[o]
__device__ __forceinline__ float reduce32(float (&z)[OUTc], int lane)
{
#pragma unroll
    for (int i = 0; i < 16; ++i) {
        const bool hi = (lane & 16) != 0;
        const float keep = hi ? z[i + 16] : z[i];
        const float send = hi ? z[i] : z[i + 16];
        z[i] = keep + __shfl_xor(send, 16);
    }
#pragma unroll
    for (int i = 0; i < 8; ++i) {
        const bool hi = (lane & 8) != 0;
        const float keep = hi ? z[i + 8] : z[i];
        const float send = hi ? z[i] : z[i + 8];
        z[i] = keep + __shfl_xor(send, 8);
    }
#pragma unroll
    for (int i = 0; i < 4; ++i) {
        const bool hi = (lane & 4) != 0;
        const float keep = hi ? z[i + 4] : z[i];
        const float send = hi ? z[i] : z[i + 4];
        z[i] = keep + __shfl_xor(send, 4);
    }
#pragma unroll
    for (int i = 0; i < 2; ++i) {
        const bool hi = (lane & 2) != 0;
        const float keep = hi ? z[i + 2] : z[i];
        const float send = hi ? z[i] : z[i + 2];
        z[i] = keep + __shfl_xor(send, 2);
    }
    {
        const bool hi = (lane & 1) != 0;
        const float keep = hi ? z[1] : z[0];
        const float send = hi ? z[0] : z[1];
        return keep + __shfl_xor(send, 1);
    }
}

// ---------------- kernel 2: fused softmax-aggregate-project ----------------
__global__ __launch_bounds__(BDIM, 3)
void fused_kernel(const float* __restrict__ x, const float* __restrict__ W,
                  const float* __restrict__ cvec, const float* __restrict__ bvec,
                  const int* __restrict__ adj, const float* __restrict__ ux,
                  int* __restrict__ cnt, float* __restrict__ out)
{
    __shared__ __align__(16) float Wl[Cc * WPAD];          // 37376 B
    __shared__ __align__(16) float qs[GPB][TPG][KSc][NBc]; // 10368 B, k-major, 48B blocks
    __shared__ __align__(16) int   js[GPB][TPG][NBc];      // 1152 B

    const int tid  = threadIdx.x;
    const int g    = tid >> 5;
    const int lane = tid & 31;
    const int h    = (tid >> 5) & 1;   // which half of the wave this group is

    // stage W into LDS, float4 (rows are 288 floats, never straddle a float4)
    {
        const float4* Wg = (const float4*)W;
        for (int i = tid; i < Cc * KSc * OUTc / 4; i += BDIM) {
            const int fi = i * 4;
            const int c  = fi / (KSc * OUTc);
            const int r  = fi - c * (KSc * OUTc);
            *(float4*)(&Wl[c * WPAD + r]) = Wg[i];
        }
    }
    float ck[KSc];
#pragma unroll
    for (int k = 0; k < KSc; ++k) ck[k] = cvec[k];
    const float bo = bvec[lane];
    __syncthreads();   // only barrier; groups loop independently afterwards

    int trip;
    if (lane == 0) trip = atomicAdd(cnt, 1);
    trip = __shfl(trip, 0, 32);

    while (trip < NTRIP) {
        const int t0 = trip * TPG;
        float inv[TPG];

        // ---- softmax phase: lanes 0..11 handle neighbor n=lane, loop over 3 tasks ----
#pragma unroll
        for (int t = 0; t < TPG; ++t) {
            const int task = t0 + t;
            bool pred = false;
            if (lane < NBc) {
                if (task < NTASK) {
                    const int bb = (task >= Vc) ? 1 : 0;
                    const int v  = task - bb * Vc;
                    const int j  = adj[v * NBc + lane];
                    pred = (j != 0);
                    const int row = pred ? (bb * Vc + j - 1) : 0;
                    js[g][t][lane] = row;
                    const float4* uo4 = (const float4*)(ux + task * UXP);
                    const float4* un4 = (const float4*)(ux + row * UXP);
                    float uo[12], un[12];
                    *(float4*)&uo[0] = uo4[0]; *(float4*)&uo[4] = uo4[1]; *(float4*)&uo[8] = uo4[2];
                    *(float4*)&un[0] = un4[0]; *(float4*)&un[4] = un4[1]; *(float4*)&un[8] = un4[2];
                    float e[KSc];
                    float mx = -3.0e38f;
#pragma unroll
                    for (int k = 0; k < KSc; ++k) {
                        e[k] = uo[k] - un[k] + ck[k];
                        mx = fmaxf(mx, e[k]);
                    }
                    float s = 0.f;
#pragma unroll
                    for (int k = 0; k < KSc; ++k) { e[k] = __expf(e[k] - mx); s += e[k]; }
                    const float r = pred ? (1.f / s) : 0.f;   // q=0 for padded neighbors
#pragma unroll
                    for (int k = 0; k < KSc; ++k) qs[g][t][k][lane] = e[k] * r;
                } else {
                    js[g][t][lane] = 0;
#pragma unroll
                    for (int k = 0; k < KSc; ++k) qs[g][t][k][lane] = 0.f;
                }
            }
            const unsigned long long bal = __ballot(pred);
            const int deg = __popc((unsigned int)(bal >> (h * 32)) & 0xFFFu);
            inv[t] = (deg > 0) ? 1.f / (float)deg : 0.f;
        }
        // same-wave LDS write->read: no barrier needed (each group reads only its own slice)

        // ---- y phase: lane=c; y[t][k] = sum_n q[t,k,n] * x[row_n, c] ----
        float y[TPG][KSc];
#pragma unroll
        for (int t = 0; t < TPG; ++t)
#pragma unroll
            for (int k = 0; k < KSc; ++k) y[t][k] = 0.f;

#pragma unroll
        for (int t = 0; t < TPG; ++t) {
            const int4* jp = (const int4*)&js[g][t][0];
            const int4 ja = jp[0], jb = jp[1], jc = jp[2];
            int rows[NBc];
            rows[0] = ja.x; rows[1] = ja.y; rows[2]  = ja.z; rows[3]  = ja.w;
            rows[4] = jb.x; rows[5] = jb.y; rows[6]  = jb.z; rows[7]  = jb.w;
            rows[8] = jc.x; rows[9] = jc.y; rows[10] = jc.z; rows[11] = jc.w;
            float xs[NBc];
#pragma unroll
            for (int n = 0; n < NBc; ++n) xs[n] = x[rows[n] * Cc + lane];
#pragma unroll
            for (int k = 0; k < KSc; ++k) {
                const float4* qp = (const float4*)&qs[g][t][k][0];
                const float4 qa = qp[0], qb = qp[1], qc = qp[2];
                float acc = 0.f;
                acc = fmaf(qa.x, xs[0], acc);  acc = fmaf(qa.y, xs[1], acc);
                acc = fmaf(qa.z, xs[2], acc);  acc = fmaf(qa.w, xs[3], acc);
                acc = fmaf(qb.x, xs[4], acc);  acc = fmaf(qb.y, xs[5], acc);
                acc = fmaf(qb.z, xs[6], acc);  acc = fmaf(qb.w, xs[7], acc);
                acc = fmaf(qc.x, xs[8], acc);  acc = fmaf(qc.y, xs[9], acc);
                acc = fmaf(qc.z, xs[10], acc); acc = fmaf(qc.w, xs[11], acc);
                y[t][k] = acc;
            }
        }

        // ---- z phase: z[t][o] = sum_k y[t][k] * W[c=lane,k,o], float4 W reads ----
        float z[TPG][OUTc];
#pragma unroll
        for (int t = 0; t < TPG; ++t)
#pragma unroll
            for (int o = 0; o < OUTc; ++o) z[t][o] = 0.f;
        const float* wrow = Wl + lane * WPAD;
#pragma unroll
        for (int k = 0; k < KSc; ++k) {
            const float a0 = y[0][k], a1 = y[1][k], a2 = y[2][k];
#pragma unroll
            for (int jj = 0; jj < 8; ++jj) {
                const float4 w4 = *(const float4*)(wrow + k * OUTc + jj * 4);
                z[0][jj*4+0] = fmaf(a0, w4.x, z[0][jj*4+0]);
                z[0][jj*4+1] = fmaf(a0, w4.y, z[0][jj*4+1]);
                z[0][jj*4+2] = fmaf(a0, w4.z, z[0][jj*4+2]);
                z[0][jj*4+3] = fmaf(a0, w4.w, z[0][jj*4+3]);
                z[1][jj*4+0] = fmaf(a1, w4.x, z[1][jj*4+0]);
                z[1][jj*4+1] = fmaf(a1, w4.y, z[1][jj*4+1]);
                z[1][jj*4+2] = fmaf(a1, w4.z, z[1][jj*4+2]);
                z[1][jj*4+3] = fmaf(a1, w4.w, z[1][jj*4+3]);
                z[2][jj*4+0] = fmaf(a2, w4.x, z[2][jj*4+0]);
                z[2][jj*4+1] = fmaf(a2, w4.y, z[2][jj*4+1]);
                z[2][jj*4+2] = fmaf(a2, w4.z, z[2][jj*4+2]);
                z[2][jj*4+3] = fmaf(a2, w4.w, z[2][jj*4+3]);
            }
        }

        // ---- cross-lane reduce over c; lane o ends with res[o]; store ----
#pragma unroll
        for (int t = 0; t < TPG; ++t) {
            const float s = reduce32(z[t], lane);
            const int task = t0 + t;
            if (task < NTASK)
                out[task * OUTc + lane] = fmaxf(fmaf(inv[t], s, bo), 0.f);
        }

        if (lane == 0) trip = atomicAdd(cnt, 1);
        trip = __shfl(trip, 0, 32);
    }
}

extern "C" void kernel_launch(void* const* d_in, const int* in_sizes, int n_in,
                              void* d_out, int out_size, void* d_ws, size_t ws_size,
                              hipStream_t stream)
{
    const float* x    = (const float*)d_in[0];
    const float* W    = (const float*)d_in[1];
    const float* u    = (const float*)d_in[2];
    const float* cvec = (const float*)d_in[3];
    const float* bvec = (const float*)d_in[4];
    const int*   adj  = (const int*)d_in[5];
    float* out = (float*)d_out;

    int*   cnt = (int*)d_ws;                       // dynamic work counter
    float* ux  = (float*)((char*)d_ws + 16);       // 40000 x 12 floats = 1.92 MB

    hipMemsetAsync(cnt, 0, 4, stream);
    ux_kernel<<<(NTASK + BDIM - 1) / BDIM, BDIM, 0, stream>>>(x, u, ux);
    fused_kernel<<<768, BDIM, 0, stream>>>(x, W, cvec, bvec, adj, ux, cnt, out);
}

// Round 3
// 232.384 us; speedup vs baseline: 1.7817x; 1.7817x over previous
//
#include <hip/hip_runtime.h>
#include <math.h>

#define BDIM 256

constexpr int Bc = 2, Vc = 20000, Cc = 32, NBc = 12, KSc = 9, OUTc = 32;
constexpr int NTASK = Bc * Vc;            // 40000
constexpr int TPG   = 2;                  // tasks per group-iteration (z[2][32] fits regs - TPG=3 spills!)
constexpr int NTRIP = NTASK / TPG;        // 20000, exact
constexpr int GPB   = 8;                  // 32-lane groups per block
constexpr int WPAD  = 292;                // row stride: %4==0 (b128-aligned), %32==4 (conflict-free)
constexpr int UXP   = 12;                 // padded ux row (16B-aligned float4 loads)

// ---------------- kernel 1: ux[row,k] = sum_c x[row,c] * u[c,k]; also zeroes cnt ----------------
__global__ __launch_bounds__(BDIM)
void ux_kernel(const float* __restrict__ x, const float* __restrict__ u,
               float* __restrict__ ux, int* __restrict__ cnt)
{
    if (blockIdx.x == 0 && threadIdx.x == 0) atomicExch(cnt, 0);  // device-scope init for fused kernel

    __shared__ float us[Cc * KSc];
    for (int i = threadIdx.x; i < Cc * KSc; i += BDIM) us[i] = u[i];
    __syncthreads();

    const int row = blockIdx.x * BDIM + threadIdx.x;
    if (row >= NTASK) return;

    const float4* xr = (const float4*)(x + row * Cc);
    float4 xv[8];
#pragma unroll
    for (int i = 0; i < 8; ++i) xv[i] = xr[i];

    float acc[KSc];
#pragma unroll
    for (int k = 0; k < KSc; ++k) acc[k] = 0.f;
#pragma unroll
    for (int c = 0; c < Cc; ++c) {
        const float xc = ((const float*)xv)[c];
#pragma unroll
        for (int k = 0; k < KSc; ++k) acc[k] = fmaf(xc, us[c * KSc + k], acc[k]);
    }
    float4* o4 = (float4*)(ux + row * UXP);
    o4[0] = make_float4(acc[0], acc[1], acc[2], acc[3]);
    o4[1] = make_float4(acc[4], acc[5], acc[6], acc[7]);
    o4[2] = make_float4(acc[8], 0.f, 0.f, 0.f);
}

// butterfly transpose-reduce: lane c enters with z[0..31]; lane o returns sum_c z_c[o]
__device__ __forceinline__ float reduce32(float (&z)[OUTc], int lane)
{
#pragma unroll
    for (int i = 0; i < 16; ++i) {
        const bool hi = (lane & 16) != 0;
        const float keep = hi ? z[i + 16] : z[i];
        const float send = hi ? z[i] : z[i + 16];
        z[i] = keep + __shfl_xor(send, 16);
    }
#pragma unroll
    for (int i = 0; i < 8; ++i) {
        const bool hi = (lane & 8) != 0;
        const float keep = hi ? z[i + 8] : z[i];
        const float send = hi ? z[i] : z[i + 8];
        z[i] = keep + __shfl_xor(send, 8);
    }
#pragma unroll
    for (int i = 0; i < 4; ++i) {
        const bool hi = (lane & 4) != 0;
        const float keep = hi ? z[i + 4] : z[i];
        const float send = hi ? z[i] : z[i + 4];
        z[i] = keep + __shfl_xor(send, 4);
    }
#pragma unroll
    for (int i = 0; i < 2; ++i) {
        const bool hi = (lane & 2) != 0;
        const float keep = hi ? z[i + 2] : z[i];
        const float send = hi ? z[i] : z[i + 2];
        z[i] = keep + __shfl_xor(send, 2);
    }
    {
        const bool hi = (lane & 1) != 0;
        const float keep = hi ? z[1] : z[0];
        const float send = hi ? z[0] : z[1];
        return keep + __shfl_xor(send, 1);
    }
}

// ---------------- kernel 2: fused softmax-aggregate-project ----------------
__global__ __launch_bounds__(BDIM, 3)
void fused_kernel(const float* __restrict__ x, const float* __restrict__ W,
                  const float* __restrict__ cvec, const float* __restrict__ bvec,
                  const int* __restrict__ adj, const float* __restrict__ ux,
                  int* __restrict__ cnt, float* __restrict__ out)
{
    __shared__ __align__(16) float Wl[Cc * WPAD];          // 37376 B
    __shared__ __align__(16) float qs[GPB][TPG][KSc][NBc]; // k-major, 48B blocks per (t,k)
    __shared__ __align__(16) int   js[GPB][TPG][NBc];

    const int tid  = threadIdx.x;
    const int g    = tid >> 5;
    const int lane = tid & 31;
    const int h    = (tid >> 5) & 1;   // which half of the wave this group occupies

    // stage W into LDS, float4 (rows are 288 floats, never straddle a float4)
    {
        const float4* Wg = (const float4*)W;
        for (int i = tid; i < Cc * KSc * OUTc / 4; i += BDIM) {
            const int fi = i * 4;
            const int c  = fi / (KSc * OUTc);
            const int r  = fi - c * (KSc * OUTc);
            *(float4*)(&Wl[c * WPAD + r]) = Wg[i];
        }
    }
    float ck[KSc];
#pragma unroll
    for (int k = 0; k < KSc; ++k) ck[k] = cvec[k];
    const float bo = bvec[lane];
    __syncthreads();   // only barrier; groups loop independently afterwards

    int trip;
    if (lane == 0) trip = atomicAdd(cnt, 1);
    trip = __shfl(trip, 0, 32);

    while (trip < NTRIP) {
        // software-pipelined work-stealing: fetch next trip NOW so the
        // cross-XCD atomic latency overlaps this iteration's body
        int next = 0;
        if (lane == 0) next = atomicAdd(cnt, 1);

        const int t0 = trip * TPG;
        float inv[TPG];

        // ---- softmax phase: lanes 0..11 handle neighbor n=lane ----
#pragma unroll
        for (int t = 0; t < TPG; ++t) {
            const int task = t0 + t;
            bool pred = false;
            if (lane < NBc) {
                const int bb = (task >= Vc) ? 1 : 0;
                const int v  = task - bb * Vc;
                const int j  = adj[v * NBc + lane];
                pred = (j != 0);
                const int row = pred ? (bb * Vc + j - 1) : 0;
                js[g][t][lane] = row;
                const float4* uo4 = (const float4*)(ux + task * UXP);
                const float4* un4 = (const float4*)(ux + row * UXP);
                float uo[12], un[12];
                *(float4*)&uo[0] = uo4[0]; *(float4*)&uo[4] = uo4[1]; *(float4*)&uo[8] = uo4[2];
                *(float4*)&un[0] = un4[0]; *(float4*)&un[4] = un4[1]; *(float4*)&un[8] = un4[2];
                float e[KSc];
                float mx = -3.0e38f;
#pragma unroll
                for (int k = 0; k < KSc; ++k) {
                    e[k] = uo[k] - un[k] + ck[k];
                    mx = fmaxf(mx, e[k]);
                }
                float s = 0.f;
#pragma unroll
                for (int k = 0; k < KSc; ++k) { e[k] = __expf(e[k] - mx); s += e[k]; }
                const float r = pred ? (1.f / s) : 0.f;   // q=0 for padded neighbors
#pragma unroll
                for (int k = 0; k < KSc; ++k) qs[g][t][k][lane] = e[k] * r;
            }
            const unsigned long long bal = __ballot(pred);
            const int deg = __popc((unsigned int)(bal >> (h * 32)) & 0xFFFu);
            inv[t] = (deg > 0) ? 1.f / (float)deg : 0.f;
        }
        // same-wave LDS write->read: no barrier needed (each group reads only its own slice)

        // ---- y phase: lane=c; y[t][k] = sum_n q[t,k,n] * x[row_n, c] ----
        float y[TPG][KSc];
#pragma unroll
        for (int t = 0; t < TPG; ++t) {
            const int4* jp = (const int4*)&js[g][t][0];
            const int4 ja = jp[0], jb = jp[1], jc = jp[2];
            int rows[NBc];
            rows[0] = ja.x; rows[1] = ja.y; rows[2]  = ja.z; rows[3]  = ja.w;
            rows[4] = jb.x; rows[5] = jb.y; rows[6]  = jb.z; rows[7]  = jb.w;
            rows[8] = jc.x; rows[9] = jc.y; rows[10] = jc.z; rows[11] = jc.w;
            float xs[NBc];
#pragma unroll
            for (int n = 0; n < NBc; ++n) xs[n] = x[rows[n] * Cc + lane];
#pragma unroll
            for (int k = 0; k < KSc; ++k) {
                const float4* qp = (const float4*)&qs[g][t][k][0];
                const float4 qa = qp[0], qb = qp[1], qc = qp[2];
                float acc = 0.f;
                acc = fmaf(qa.x, xs[0], acc);  acc = fmaf(qa.y, xs[1], acc);
                acc = fmaf(qa.z, xs[2], acc);  acc = fmaf(qa.w, xs[3], acc);
                acc = fmaf(qb.x, xs[4], acc);  acc = fmaf(qb.y, xs[5], acc);
                acc = fmaf(qb.z, xs[6], acc);  acc = fmaf(qb.w, xs[7], acc);
                acc = fmaf(qc.x, xs[8], acc);  acc = fmaf(qc.y, xs[9], acc);
                acc = fmaf(qc.z, xs[10], acc); acc = fmaf(qc.w, xs[11], acc);
                y[t][k] = acc;
            }
        }

        // ---- z phase: z[t][o] = sum_k y[t][k] * W[c=lane,k,o], float4 W reads shared by both tasks ----
        float z0[OUTc], z1[OUTc];
#pragma unroll
        for (int o = 0; o < OUTc; ++o) { z0[o] = 0.f; z1[o] = 0.f; }
        const float* wrow = Wl + lane * WPAD;
#pragma unroll
        for (int k = 0; k < KSc; ++k) {
            const float a0 = y[0][k], a1 = y[1][k];
#pragma unroll
            for (int jj = 0; jj < 8; ++jj) {
                const float4 w4 = *(const float4*)(wrow + k * OUTc + jj * 4);
                z0[jj*4+0] = fmaf(a0, w4.x, z0[jj*4+0]);
                z0[jj*4+1] = fmaf(a0, w4.y, z0[jj*4+1]);
                z0[jj*4+2] = fmaf(a0, w4.z, z0[jj*4+2]);
                z0[jj*4+3] = fmaf(a0, w4.w, z0[jj*4+3]);
                z1[jj*4+0] = fmaf(a1, w4.x, z1[jj*4+0]);
                z1[jj*4+1] = fmaf(a1, w4.y, z1[jj*4+1]);
                z1[jj*4+2] = fmaf(a1, w4.z, z1[jj*4+2]);
                z1[jj*4+3] = fmaf(a1, w4.w, z1[jj*4+3]);
            }
        }

        // ---- cross-lane reduce over c; lane o ends with res[o]; coalesced store ----
        {
            const float s0 = reduce32(z0, lane);
            out[t0 * OUTc + lane] = fmaxf(fmaf(inv[0], s0, bo), 0.f);
            const float s1 = reduce32(z1, lane);
            out[(t0 + 1) * OUTc + lane] = fmaxf(fmaf(inv[1], s1, bo), 0.f);
        }

        trip = __shfl(next, 0, 32);
    }
}

extern "C" void kernel_launch(void* const* d_in, const int* in_sizes, int n_in,
                              void* d_out, int out_size, void* d_ws, size_t ws_size,
                              hipStream_t stream)
{
    const float* x    = (const float*)d_in[0];
    const float* W    = (const float*)d_in[1];
    const float* u    = (const float*)d_in[2];
    const float* cvec = (const float*)d_in[3];
    const float* bvec = (const float*)d_in[4];
    const int*   adj  = (const int*)d_in[5];
    float* out = (float*)d_out;

    int*   cnt = (int*)d_ws;                  // dynamic work counter (zeroed by ux_kernel)
    float* ux  = (float*)((char*)d_ws + 256); // 40000 x 12 floats = 1.92 MB

    ux_kernel<<<(NTASK + BDIM - 1) / BDIM, BDIM, 0, stream>>>(x, u, ux, cnt);
    fused_kernel<<<768, BDIM, 0, stream>>>(x, W, cvec, bvec, adj, ux, cnt, out);
}

// Round 4
// 96.067 us; speedup vs baseline: 4.3099x; 2.4190x over previous
//
#include <hip/hip_runtime.h>
#include <math.h>

#define BDIM 256

constexpr int Bc = 2, Vc = 20000, Cc = 32, NBc = 12, KSc = 9, OUTc = 32;
constexpr int NTASK = Bc * Vc;            // 40000
constexpr int TPG   = 2;                  // tasks per group-iteration (TPG=3 spills — round 2)
constexpr int NTRIP = NTASK / TPG;        // 20000, exact
constexpr int GPB   = 8;                  // 32-lane groups per block
constexpr int GRID  = 768;                // 3 blocks/CU resident
constexpr int NSLOT = GRID * GPB;         // 6144 static slots (NO atomics — round 3 lesson)
constexpr int WPAD  = 292;                // row stride: %4==0 (b128-aligned), %32==4 (conflict-free)
constexpr int UXP   = 12;                 // padded ux row (16B-aligned float4 loads)

// ---------------- kernel 1: ux[row,k] = sum_c x[row,c] * u[c,k] ----------------
__global__ __launch_bounds__(BDIM)
void ux_kernel(const float* __restrict__ x, const float* __restrict__ u,
               float* __restrict__ ux)
{
    __shared__ float us[Cc * KSc];
    for (int i = threadIdx.x; i < Cc * KSc; i += BDIM) us[i] = u[i];
    __syncthreads();

    const int row = blockIdx.x * BDIM + threadIdx.x;
    if (row >= NTASK) return;

    const float4* xr = (const float4*)(x + row * Cc);
    float4 xv[8];
#pragma unroll
    for (int i = 0; i < 8; ++i) xv[i] = xr[i];

    float acc[KSc];
#pragma unroll
    for (int k = 0; k < KSc; ++k) acc[k] = 0.f;
#pragma unroll
    for (int c = 0; c < Cc; ++c) {
        const float xc = ((const float*)xv)[c];
#pragma unroll
        for (int k = 0; k < KSc; ++k) acc[k] = fmaf(xc, us[c * KSc + k], acc[k]);
    }
    float4* o4 = (float4*)(ux + row * UXP);
    o4[0] = make_float4(acc[0], acc[1], acc[2], acc[3]);
    o4[1] = make_float4(acc[4], acc[5], acc[6], acc[7]);
    o4[2] = make_float4(acc[8], 0.f, 0.f, 0.f);
}

// butterfly transpose-reduce: lane c enters with z[0..31]; lane o returns sum_c z_c[o]
__device__ __forceinline__ float reduce32(float (&z)[OUTc], int lane)
{
#pragma unroll
    for (int i = 0; i < 16; ++i) {
        const bool hi = (lane & 16) != 0;
        const float keep = hi ? z[i + 16] : z[i];
        const float send = hi ? z[i] : z[i + 16];
        z[i] = keep + __shfl_xor(send, 16);
    }
#pragma unroll
    for (int i = 0; i < 8; ++i) {
        const bool hi = (lane & 8) != 0;
        const float keep = hi ? z[i + 8] : z[i];
        const float send = hi ? z[i] : z[i + 8];
        z[i] = keep + __shfl_xor(send, 8);
    }
#pragma unroll
    for (int i = 0; i < 4; ++i) {
        const bool hi = (lane & 4) != 0;
        const float keep = hi ? z[i + 4] : z[i];
        const float send = hi ? z[i] : z[i + 4];
        z[i] = keep + __shfl_xor(send, 4);
    }
#pragma unroll
    for (int i = 0; i < 2; ++i) {
        const bool hi = (lane & 2) != 0;
        const float keep = hi ? z[i + 2] : z[i];
        const float send = hi ? z[i] : z[i + 2];
        z[i] = keep + __shfl_xor(send, 2);
    }
    {
        const bool hi = (lane & 1) != 0;
        const float keep = hi ? z[1] : z[0];
        const float send = hi ? z[0] : z[1];
        return keep + __shfl_xor(send, 1);
    }
}

// ---------------- kernel 2: fused softmax-aggregate-project ----------------
__global__ __launch_bounds__(BDIM, 3)
void fused_kernel(const float* __restrict__ x, const float* __restrict__ W,
                  const float* __restrict__ cvec, const float* __restrict__ bvec,
                  const int* __restrict__ adj, const float* __restrict__ ux,
                  float* __restrict__ out)
{
    __shared__ __align__(16) float Wl[Cc * WPAD];          // 37376 B
    __shared__ __align__(16) float qs[GPB][TPG][KSc][NBc]; // k-major, 48B blocks per (t,k)
    __shared__ __align__(16) int   js[GPB][TPG][NBc];

    const int tid  = threadIdx.x;
    const int g    = tid >> 5;
    const int lane = tid & 31;
    const int h    = (tid >> 5) & 1;   // which half of the wave this group occupies

    // stage W into LDS, float4 (rows are 288 floats, never straddle a float4)
    {
        const float4* Wg = (const float4*)W;
        for (int i = tid; i < Cc * KSc * OUTc / 4; i += BDIM) {
            const int fi = i * 4;
            const int c  = fi / (KSc * OUTc);
            const int r  = fi - c * (KSc * OUTc);
            *(float4*)(&Wl[c * WPAD + r]) = Wg[i];
        }
    }
    float ck[KSc];
#pragma unroll
    for (int k = 0; k < KSc; ++k) ck[k] = cvec[k];
    const float bo = bvec[lane];
    __syncthreads();   // only barrier; groups loop independently afterwards

    const int slot0 = blockIdx.x * GPB + g;

    for (int trip = slot0; trip < NTRIP; trip += NSLOT) {
        const int t0 = trip * TPG;

        // ---- softmax phase: lanes 0..23 cover 2 tasks x 12 neighbors in one pass ----
        bool pred = false;
        if (lane < 2 * NBc) {
            const int t    = (lane >= NBc) ? 1 : 0;
            const int n    = lane - t * NBc;
            const int task = t0 + t;
            const int bb   = (task >= Vc) ? 1 : 0;
            const int v    = task - bb * Vc;
            const int j    = adj[v * NBc + n];
            pred = (j != 0);
            const int row = pred ? (bb * Vc + j - 1) : 0;
            js[g][t][n] = row;
            const float4* uo4 = (const float4*)(ux + task * UXP);
            const float4* un4 = (const float4*)(ux + row * UXP);
            float uo[12], un[12];
            *(float4*)&uo[0] = uo4[0]; *(float4*)&uo[4] = uo4[1]; *(float4*)&uo[8] = uo4[2];
            *(float4*)&un[0] = un4[0]; *(float4*)&un[4] = un4[1]; *(float4*)&un[8] = un4[2];
            float e[KSc];
            float mx = -3.0e38f;
#pragma unroll
            for (int k = 0; k < KSc; ++k) {
                e[k] = uo[k] - un[k] + ck[k];
                mx = fmaxf(mx, e[k]);
            }
            float s = 0.f;
#pragma unroll
            for (int k = 0; k < KSc; ++k) { e[k] = __expf(e[k] - mx); s += e[k]; }
            const float r = pred ? (1.f / s) : 0.f;   // q=0 for padded neighbors
#pragma unroll
            for (int k = 0; k < KSc; ++k) qs[g][t][k][n] = e[k] * r;
        }
        const unsigned long long bal = __ballot(pred);
        const unsigned int mg = (unsigned int)(bal >> (h * 32));
        const int deg0 = __popc(mg & 0xFFFu);
        const int deg1 = __popc((mg >> NBc) & 0xFFFu);
        const float inv0 = (deg0 > 0) ? 1.f / (float)deg0 : 0.f;
        const float inv1 = (deg1 > 0) ? 1.f / (float)deg1 : 0.f;
        // same-wave LDS write->read: no barrier needed (each group reads only its own slice)

        // ---- y phase: lane=c; y[t][k] = sum_n q[t,k,n] * x[row_n, c] ----
        float y[TPG][KSc];
#pragma unroll
        for (int t = 0; t < TPG; ++t) {
            const int4* jp = (const int4*)&js[g][t][0];
            const int4 ja = jp[0], jb = jp[1], jc = jp[2];
            int rows[NBc];
            rows[0] = ja.x; rows[1] = ja.y; rows[2]  = ja.z; rows[3]  = ja.w;
            rows[4] = jb.x; rows[5] = jb.y; rows[6]  = jb.z; rows[7]  = jb.w;
            rows[8] = jc.x; rows[9] = jc.y; rows[10] = jc.z; rows[11] = jc.w;
            float xs[NBc];
#pragma unroll
            for (int n = 0; n < NBc; ++n) xs[n] = x[rows[n] * Cc + lane];
#pragma unroll
            for (int k = 0; k < KSc; ++k) {
                const float4* qp = (const float4*)&qs[g][t][k][0];
                const float4 qa = qp[0], qb = qp[1], qc = qp[2];
                float acc = 0.f;
                acc = fmaf(qa.x, xs[0], acc);  acc = fmaf(qa.y, xs[1], acc);
                acc = fmaf(qa.z, xs[2], acc);  acc = fmaf(qa.w, xs[3], acc);
                acc = fmaf(qb.x, xs[4], acc);  acc = fmaf(qb.y, xs[5], acc);
                acc = fmaf(qb.z, xs[6], acc);  acc = fmaf(qb.w, xs[7], acc);
                acc = fmaf(qc.x, xs[8], acc);  acc = fmaf(qc.y, xs[9], acc);
                acc = fmaf(qc.z, xs[10], acc); acc = fmaf(qc.w, xs[11], acc);
                y[t][k] = acc;
            }
        }

        // ---- z phase: z[t][o] = sum_k y[t][k] * W[c=lane,k,o]; each float4 W read feeds 2 tasks ----
        float z0[OUTc], z1[OUTc];
#pragma unroll
        for (int o = 0; o < OUTc; ++o) { z0[o] = 0.f; z1[o] = 0.f; }
        const float* wrow = Wl + lane * WPAD;
#pragma unroll
        for (int k = 0; k < KSc; ++k) {
            const float a0 = y[0][k], a1 = y[1][k];
#pragma unroll
            for (int jj = 0; jj < 8; ++jj) {
                const float4 w4 = *(const float4*)(wrow + k * OUTc + jj * 4);
                z0[jj*4+0] = fmaf(a0, w4.x, z0[jj*4+0]);
                z0[jj*4+1] = fmaf(a0, w4.y, z0[jj*4+1]);
                z0[jj*4+2] = fmaf(a0, w4.z, z0[jj*4+2]);
                z0[jj*4+3] = fmaf(a0, w4.w, z0[jj*4+3]);
                z1[jj*4+0] = fmaf(a1, w4.x, z1[jj*4+0]);
                z1[jj*4+1] = fmaf(a1, w4.y, z1[jj*4+1]);
                z1[jj*4+2] = fmaf(a1, w4.z, z1[jj*4+2]);
                z1[jj*4+3] = fmaf(a1, w4.w, z1[jj*4+3]);
            }
        }

        // ---- cross-lane reduce over c; lane o ends with res[o]; coalesced store ----
        {
            const float s0 = reduce32(z0, lane);
            out[t0 * OUTc + lane] = fmaxf(fmaf(inv0, s0, bo), 0.f);
            const float s1 = reduce32(z1, lane);
            out[(t0 + 1) * OUTc + lane] = fmaxf(fmaf(inv1, s1, bo), 0.f);
        }
    }
}

extern "C" void kernel_launch(void* const* d_in, const int* in_sizes, int n_in,
                              void* d_out, int out_size, void* d_ws, size_t ws_size,
                              hipStream_t stream)
{
    const float* x    = (const float*)d_in[0];
    const float* W    = (const float*)d_in[1];
    const float* u    = (const float*)d_in[2];
    const float* cvec = (const float*)d_in[3];
    const float* bvec = (const float*)d_in[4];
    const int*   adj  = (const int*)d_in[5];
    float* out = (float*)d_out;

    float* ux = (float*)d_ws;   // 40000 x 12 floats = 1.92 MB scratch

    ux_kernel<<<(NTASK + BDIM - 1) / BDIM, BDIM, 0, stream>>>(x, u, ux);
    fused_kernel<<<GRID, BDIM, 0, stream>>>(x, W, cvec, bvec, adj, ux, out);
}